// Round 1
// baseline (1463.373 us; speedup 1.0000x reference)
//
#include <hip/hip_runtime.h>

typedef short s16x8 __attribute__((ext_vector_type(8)));
typedef float f32x4 __attribute__((ext_vector_type(4)));
typedef unsigned short u16;

static __device__ __forceinline__ f32x4 mfma16(s16x8 a, s16x8 b, f32x4 c) {
  return __builtin_amdgcn_mfma_f32_16x16x32_bf16(a, b, c, 0, 0, 0);
}

// fp32 -> bf16 round-to-nearest-even
static __device__ __forceinline__ u16 f2b(float f) {
  union { float f; unsigned int u; } v; v.f = f;
  unsigned int u = v.u;
  return (u16)((u + 0x7fffu + ((u >> 16) & 1u)) >> 16);
}

// ---------------------------------------------------------------------------
// Generic small GEMM: C[M][N] = A[M][K] @ B[K][N]  (fp32 in, bf16 staged, fp32 acc)
// MODE 0: store bf16 C row-major
// MODE 1: store fp32 C TRANSPOSED (C^T [N][M])
// MODE 2: store fp32 C row-major, += bias[n]
// Requires M%64==0, N%64==0, K%32==0.
// ---------------------------------------------------------------------------
template<int MODE>
__global__ __launch_bounds__(256)
void gemm_pre(const float* __restrict__ A, const float* __restrict__ B,
              void* __restrict__ Cout, const float* __restrict__ bias,
              int M, int N, int K) {
  __shared__ u16 As[64][40];
  __shared__ u16 BsT[64][40];
  const int m0 = blockIdx.y << 6, n0 = blockIdx.x << 6;
  const int tid = threadIdx.x;
  const int wave = tid >> 6, lane = tid & 63;
  const int quad = lane >> 4, l16 = lane & 15;
  f32x4 acc[4] = {{0,0,0,0},{0,0,0,0},{0,0,0,0},{0,0,0,0}};
  for (int k0 = 0; k0 < K; k0 += 32) {
    __syncthreads();
    { // stage A tile 64x32
      const int r = tid >> 2, cs = (tid & 3) << 3;
      const float* ap = A + (size_t)(m0 + r) * K + k0 + cs;
      float4 v0 = *(const float4*)ap, v1 = *(const float4*)(ap + 4);
      As[r][cs+0] = f2b(v0.x); As[r][cs+1] = f2b(v0.y);
      As[r][cs+2] = f2b(v0.z); As[r][cs+3] = f2b(v0.w);
      As[r][cs+4] = f2b(v1.x); As[r][cs+5] = f2b(v1.y);
      As[r][cs+6] = f2b(v1.z); As[r][cs+7] = f2b(v1.w);
    }
    { // stage B tile 32x64 transposed -> BsT[n][k]
      const int kk = tid >> 3, ns = (tid & 7) << 3;
      const float* bp = B + (size_t)(k0 + kk) * N + n0 + ns;
      float4 v0 = *(const float4*)bp, v1 = *(const float4*)(bp + 4);
      BsT[ns+0][kk] = f2b(v0.x); BsT[ns+1][kk] = f2b(v0.y);
      BsT[ns+2][kk] = f2b(v0.z); BsT[ns+3][kk] = f2b(v0.w);
      BsT[ns+4][kk] = f2b(v1.x); BsT[ns+5][kk] = f2b(v1.y);
      BsT[ns+6][kk] = f2b(v1.z); BsT[ns+7][kk] = f2b(v1.w);
    }
    __syncthreads();
    const s16x8 af = *(const s16x8*)&As[(wave << 4) + l16][quad << 3];
    #pragma unroll
    for (int nt = 0; nt < 4; nt++) {
      const s16x8 bfr = *(const s16x8*)&BsT[(nt << 4) + l16][quad << 3];
      acc[nt] = mfma16(af, bfr, acc[nt]);
    }
  }
  const int mrow = m0 + (wave << 4) + (quad << 2);
  #pragma unroll
  for (int nt = 0; nt < 4; nt++) {
    const int n = n0 + (nt << 4) + l16;
    float badd = 0.f;
    if (MODE == 2) badd = bias[n];
    #pragma unroll
    for (int r = 0; r < 4; r++) {
      float v = acc[nt][r] + badd;
      if (MODE == 0)      ((u16*)Cout)[(size_t)(mrow + r) * N + n] = f2b(v);
      else if (MODE == 1) ((float*)Cout)[(size_t)n * M + (mrow + r)] = v;
      else                ((float*)Cout)[(size_t)(mrow + r) * N + n] = v;
    }
  }
}

// out[j] = sum_k A[j][k]*v[k] + c[j]   (tiny fp32 bias folds)
__global__ __launch_bounds__(256)
void bias_dot(const float* __restrict__ A, const float* __restrict__ v,
              const float* __restrict__ c, float* __restrict__ out,
              int M, int K) {
  int j = blockIdx.x * 256 + threadIdx.x;
  if (j >= M) return;
  const float* ar = A + (size_t)j * K;
  float acc = 0.f;
  for (int k = 0; k < K; k += 4) {
    float4 w = *(const float4*)(ar + k);
    acc += w.x * v[k] + w.y * v[k+1] + w.z * v[k+2] + w.w * v[k+3];
  }
  out[j] = acc + c[j];
}

// ---------------------------------------------------------------------------
// Fused per-cell attention. One workgroup (256 thr, 4 waves) per cell.
// ---------------------------------------------------------------------------
template<int MT>
static __device__ __forceinline__ void heads_loop(
    const u16* __restrict__ Wqkv, const float* __restrict__ b_eff,
    u16 (*Xs)[776], u16 (*Qs)[72], u16 (*Ks)[72], u16 (*VTs)[72],
    u16 (*Ps)[72], float (*Sf)[65], float* pooled,
    const int len, const float invLen, const int tid) {
  const int wave = tid >> 6, lane = tid & 63;
  const int quad = lane >> 4, l16 = lane & 15;
  constexpr int LR = MT * 16;
  constexpr int KPV = (LR + 31) / 32;    // K-steps for P@V (1 or 2)
  const float scale = 0.125f;            // 1/sqrt(64)

  for (int h = 0; h < 8; h++) {
    // ---- fused QKV projection for head h: [LR x 768] @ [768 x 192]^T ----
    // wave owns n-tiles {3w,3w+1,3w+2} of 12 (cols: 0-63=Q, 64-127=K, 128-191=V)
    f32x4 acc[3][MT];
    #pragma unroll
    for (int it = 0; it < 3; it++)
      #pragma unroll
      for (int im = 0; im < MT; im++) acc[it][im] = (f32x4){0.f,0.f,0.f,0.f};
    int grow[3], jcol[3];
    #pragma unroll
    for (int it = 0; it < 3; it++) {
      const int j = ((wave * 3 + it) << 4) + l16;   // 0..191
      const int sec = j >> 6;                       // 0=q 1=k 2=v
      grow[it] = (sec << 9) + (h << 6) + (j & 63);  // row in Wqkv_eff[1536][768]
      jcol[it] = j;
    }
    s16x8 bcur[3];
    #pragma unroll
    for (int it = 0; it < 3; it++)
      bcur[it] = *(const s16x8*)(Wqkv + (size_t)grow[it] * 768 + (quad << 3));
    for (int ks = 0; ks < 24; ks++) {
      s16x8 bnext[3];
      const int ksn = (ks < 23) ? (ks + 1) : 23;    // prefetch next K-step's weights
      #pragma unroll
      for (int it = 0; it < 3; it++)
        bnext[it] = *(const s16x8*)(Wqkv + (size_t)grow[it] * 768 + (ksn << 5) + (quad << 3));
      s16x8 af[MT];
      #pragma unroll
      for (int im = 0; im < MT; im++)
        af[im] = *(const s16x8*)&Xs[(im << 4) + l16][(ks << 5) + (quad << 3)];
      #pragma unroll
      for (int it = 0; it < 3; it++)
        #pragma unroll
        for (int im = 0; im < MT; im++)
          acc[it][im] = mfma16(af[im], bcur[it], acc[it][im]);
      bcur[0] = bnext[0]; bcur[1] = bnext[1]; bcur[2] = bnext[2];
    }
    // epilogue: +bias, store Q/K row-major, V transposed (VT[d][m])
    #pragma unroll
    for (int it = 0; it < 3; it++) {
      const float badd = b_eff[grow[it]];
      const int j = jcol[it];
      #pragma unroll
      for (int im = 0; im < MT; im++) {
        const int rb = (im << 4) + (quad << 2);
        if (j < 64) {
          #pragma unroll
          for (int r = 0; r < 4; r++) Qs[rb + r][j] = f2b(acc[it][im][r] + badd);
        } else if (j < 128) {
          #pragma unroll
          for (int r = 0; r < 4; r++) Ks[rb + r][j - 64] = f2b(acc[it][im][r] + badd);
        } else {
          ushort4 hv;
          hv.x = f2b(acc[it][im][0] + badd);
          hv.y = f2b(acc[it][im][1] + badd);
          hv.z = f2b(acc[it][im][2] + badd);
          hv.w = f2b(acc[it][im][3] + badd);
          *(ushort4*)&VTs[j - 128][rb] = hv;
        }
      }
    }
    __syncthreads();
    // ---- S = Q K^T (fp32 into Sf) ----
    for (int item = wave; item < MT * MT; item += 4) {
      const int mq = item / MT, mk = item - mq * MT;
      f32x4 sacc = (f32x4){0.f,0.f,0.f,0.f};
      #pragma unroll
      for (int ks = 0; ks < 2; ks++) {
        const s16x8 a = *(const s16x8*)&Qs[(mq << 4) + l16][(ks << 5) + (quad << 3)];
        const s16x8 b = *(const s16x8*)&Ks[(mk << 4) + l16][(ks << 5) + (quad << 3)];
        sacc = mfma16(a, b, sacc);
      }
      const int col = (mk << 4) + l16;
      const int rb = (mq << 4) + (quad << 2);
      #pragma unroll
      for (int r = 0; r < 4; r++) Sf[rb + r][col] = sacc[r];
    }
    __syncthreads();
    // ---- softmax over valid keys (cols < len); P in bf16 (cols>=len stay 0) ----
    if (tid < LR) {
      float mx = -1e30f;
      for (int m = 0; m < len; m++) mx = fmaxf(mx, Sf[tid][m]);
      float sum = 0.f;
      for (int m = 0; m < len; m++) {
        const float e = __expf((Sf[tid][m] - mx) * scale);
        Sf[tid][m] = e;
        sum += e;
      }
      const float inv = 1.0f / sum;
      for (int m = 0; m < len; m++) Ps[tid][m] = f2b(Sf[tid][m] * inv);
    }
    __syncthreads();
    // ---- ctx = P @ V (via VT), fp32 into Sf ----
    for (int item = wave; item < MT * 4; item += 4) {
      const int mq = item >> 2, nd = item & 3;
      f32x4 cacc = (f32x4){0.f,0.f,0.f,0.f};
      #pragma unroll
      for (int ks = 0; ks < KPV; ks++) {
        const s16x8 a = *(const s16x8*)&Ps[(mq << 4) + l16][(ks << 5) + (quad << 3)];
        const s16x8 b = *(const s16x8*)&VTs[(nd << 4) + l16][(ks << 5) + (quad << 3)];
        cacc = mfma16(a, b, cacc);
      }
      const int col = (nd << 4) + l16;
      const int rb = (mq << 4) + (quad << 2);
      #pragma unroll
      for (int r = 0; r < 4; r++) Sf[rb + r][col] = cacc[r];
    }
    __syncthreads();
    // ---- masked mean-pool ----
    if (tid < 64) {
      float s = 0.f;
      for (int l = 0; l < len; l++) s += Sf[l][tid];
      pooled[(h << 6) + tid] = s * invLen;
    }
    __syncthreads();
  }
}

__global__ __launch_bounds__(256, 1)
void cell_attn(const float* __restrict__ chunk, const u16* __restrict__ Wqkv,
               const float* __restrict__ b_eff, const int* __restrict__ cell_idx,
               const int* __restrict__ cell_len, float* __restrict__ pooled_g) {
  __shared__ u16 Xs[64][776];     // gathered chunk rows, bf16, +8 pad (2-way banks)
  __shared__ u16 Qs[64][72];
  __shared__ u16 Ks[64][72];
  __shared__ u16 VTs[64][72];     // V transposed: [d][m]
  __shared__ u16 Ps[64][72];      // softmax probs, bf16, A-layout
  __shared__ float Sf[64][65];    // scores / ctx staging, fp32
  __shared__ float pooled[512];
  __shared__ int idx_s[64];

  const int c = blockIdx.x;
  const int tid = threadIdx.x;

  int len = cell_len[c];
  len = (len < 1) ? 1 : ((len > 64) ? 64 : len);
  const int mt = (len + 15) >> 4;
  const int Lr = mt << 4;
  const float invLen = 1.0f / (float)len;

  if (tid < 64) idx_s[tid] = cell_idx[(c << 6) + tid];
  __syncthreads();

  // gather + fp32->bf16 convert valid rows
  for (int i = tid; i < len * 192; i += 256) {
    const int r = i / 192;
    const int c4 = i - r * 192;
    const float4 f = *(const float4*)(chunk + (size_t)idx_s[r] * 768 + (c4 << 2));
    ushort4 hv; hv.x = f2b(f.x); hv.y = f2b(f.y); hv.z = f2b(f.z); hv.w = f2b(f.w);
    *(ushort4*)&Xs[r][c4 << 2] = hv;
  }
  const ushort4 z4 = {0, 0, 0, 0};
  // zero pad rows [len, Lr) so tile-rounded MFMA stays finite
  for (int i = tid; i < (Lr - len) * 192; i += 256) {
    const int r = len + i / 192;
    const int c4 = i - (i / 192) * 192;
    *(ushort4*)&Xs[r][c4 << 2] = z4;
  }
  // zero P and VT once per cell (cols >= len must contribute exactly 0 to P@V)
  for (int i = tid; i < 1152; i += 256) *(ushort4*)(&Ps[0][0] + (i << 2)) = z4;
  for (int i = tid; i < 1152; i += 256) *(ushort4*)(&VTs[0][0] + (i << 2)) = z4;
  __syncthreads();

  switch (mt) {
    case 1: heads_loop<1>(Wqkv, b_eff, Xs, Qs, Ks, VTs, Ps, Sf, pooled, len, invLen, tid); break;
    case 2: heads_loop<2>(Wqkv, b_eff, Xs, Qs, Ks, VTs, Ps, Sf, pooled, len, invLen, tid); break;
    case 3: heads_loop<3>(Wqkv, b_eff, Xs, Qs, Ks, VTs, Ps, Sf, pooled, len, invLen, tid); break;
    default: heads_loop<4>(Wqkv, b_eff, Xs, Qs, Ks, VTs, Ps, Sf, pooled, len, invLen, tid); break;
  }

  for (int i = tid; i < 512; i += 256) pooled_g[((size_t)c << 9) + i] = pooled[i];
}

// ---------------------------------------------------------------------------
extern "C" void kernel_launch(void* const* d_in, const int* in_sizes, int n_in,
                              void* d_out, int out_size, void* d_ws, size_t ws_size,
                              hipStream_t stream) {
  const float* chunk  = (const float*)d_in[0];
  const float* Wq     = (const float*)d_in[1];
  const float* bq     = (const float*)d_in[2];
  const float* Wk     = (const float*)d_in[3];
  const float* bk     = (const float*)d_in[4];
  const float* Wv     = (const float*)d_in[5];
  const float* bv     = (const float*)d_in[6];
  const float* W_in   = (const float*)d_in[7];
  const float* b_in   = (const float*)d_in[8];
  const float* Wo     = (const float*)d_in[9];
  const float* bo     = (const float*)d_in[10];
  const float* Wout   = (const float*)d_in[11];
  const float* bout   = (const float*)d_in[12];
  const int* cell_idx = (const int*)d_in[13];
  const int* cell_len = (const int*)d_in[14];

  // workspace layout (~6.8 MB)
  char* ws = (char*)d_ws;
  u16*   Wqkv   = (u16*)(ws + 0);              // [1536][768] bf16 fused qkv weights
  float* b_eff  = (float*)(ws + 2359296);      // [1536] fused qkv bias
  float* WfT    = (float*)(ws + 2365440);      // [512][256] (Wout@Wo)^T fp32
  float* bfe    = (float*)(ws + 2889728);      // [256] Wout@bo + bout
  float* pooled = (float*)(ws + 2890752);      // [2048][512] fp32

  dim3 blk(256);
  // fused projection weights: W{q,k,v}_eff = W_in[block] @ W{q,k,v}
  dim3 g1(12, 8);
  gemm_pre<0><<<g1, blk, 0, stream>>>(W_in,            Wq, (void*)(Wqkv),            nullptr, 512, 768, 512);
  gemm_pre<0><<<g1, blk, 0, stream>>>(W_in + 512*512,  Wk, (void*)(Wqkv + 512*768),  nullptr, 512, 768, 512);
  gemm_pre<0><<<g1, blk, 0, stream>>>(W_in + 1024*512, Wv, (void*)(Wqkv + 1024*768), nullptr, 512, 768, 512);
  // WfT = (Wout @ Wo)^T, fp32
  dim3 g2(8, 4);
  gemm_pre<1><<<g2, blk, 0, stream>>>(Wout, Wo, (void*)WfT, nullptr, 256, 512, 512);
  // fused biases
  bias_dot<<<dim3(2), blk, 0, stream>>>(W_in,            bq, b_in,        b_eff,        512, 512);
  bias_dot<<<dim3(2), blk, 0, stream>>>(W_in + 512*512,  bk, b_in + 512,  b_eff + 512,  512, 512);
  bias_dot<<<dim3(2), blk, 0, stream>>>(W_in + 1024*512, bv, b_in + 1024, b_eff + 1024, 512, 512);
  bias_dot<<<dim3(1), blk, 0, stream>>>(Wout, bo, bout, bfe, 256, 512);
  // fused per-cell gather + QKV + attention + pool
  cell_attn<<<dim3(2048), blk, 0, stream>>>(chunk, Wqkv, b_eff, cell_idx, cell_len, pooled);
  // final: out = pooled @ WfT + bfe
  dim3 g3(4, 32);
  gemm_pre<2><<<g3, blk, 0, stream>>>(pooled, WfT, d_out, bfe, 2048, 256, 512);
}

// Round 2
// 725.338 us; speedup vs baseline: 2.0175x; 2.0175x over previous
//
#include <hip/hip_runtime.h>

typedef short s16x8 __attribute__((ext_vector_type(8)));
typedef float f32x4 __attribute__((ext_vector_type(4)));
typedef unsigned short u16;

static __device__ __forceinline__ f32x4 mfma16(s16x8 a, s16x8 b, f32x4 c) {
  return __builtin_amdgcn_mfma_f32_16x16x32_bf16(a, b, c, 0, 0, 0);
}

// fp32 -> bf16 round-to-nearest-even
static __device__ __forceinline__ u16 f2b(float f) {
  union { float f; unsigned int u; } v; v.f = f;
  unsigned int u = v.u;
  return (u16)((u + 0x7fffu + ((u >> 16) & 1u)) >> 16);
}

// async global->LDS, 16B per lane; LDS dest = wave-uniform base + lane*16
static __device__ __forceinline__ void gld_lds16(const void* g, void* l) {
  __builtin_amdgcn_global_load_lds(
      (const __attribute__((address_space(1))) void*)g,
      (__attribute__((address_space(3))) void*)l, 16, 0, 0);
}

// ---------------------------------------------------------------------------
// Generic small GEMM: C[M][N] = A[M][K] @ B[K][N]  (fp32 in, bf16 staged, fp32 acc)
// MODE 0: store bf16 C row-major
// MODE 1: store fp32 C TRANSPOSED (C^T [N][M])
// MODE 2: store fp32 C row-major, += bias[n]
// Requires M%64==0, N%64==0, K%32==0.
// ---------------------------------------------------------------------------
template<int MODE>
__global__ __launch_bounds__(256)
void gemm_pre(const float* __restrict__ A, const float* __restrict__ B,
              void* __restrict__ Cout, const float* __restrict__ bias,
              int M, int N, int K) {
  __shared__ u16 As[64][40];
  __shared__ u16 BsT[64][40];
  const int m0 = blockIdx.y << 6, n0 = blockIdx.x << 6;
  const int tid = threadIdx.x;
  const int wave = tid >> 6, lane = tid & 63;
  const int quad = lane >> 4, l16 = lane & 15;
  f32x4 acc[4] = {{0,0,0,0},{0,0,0,0},{0,0,0,0},{0,0,0,0}};
  for (int k0 = 0; k0 < K; k0 += 32) {
    __syncthreads();
    { // stage A tile 64x32
      const int r = tid >> 2, cs = (tid & 3) << 3;
      const float* ap = A + (size_t)(m0 + r) * K + k0 + cs;
      float4 v0 = *(const float4*)ap, v1 = *(const float4*)(ap + 4);
      As[r][cs+0] = f2b(v0.x); As[r][cs+1] = f2b(v0.y);
      As[r][cs+2] = f2b(v0.z); As[r][cs+3] = f2b(v0.w);
      As[r][cs+4] = f2b(v1.x); As[r][cs+5] = f2b(v1.y);
      As[r][cs+6] = f2b(v1.z); As[r][cs+7] = f2b(v1.w);
    }
    { // stage B tile 32x64 transposed -> BsT[n][k]
      const int kk = tid >> 3, ns = (tid & 7) << 3;
      const float* bp = B + (size_t)(k0 + kk) * N + n0 + ns;
      float4 v0 = *(const float4*)bp, v1 = *(const float4*)(bp + 4);
      BsT[ns+0][kk] = f2b(v0.x); BsT[ns+1][kk] = f2b(v0.y);
      BsT[ns+2][kk] = f2b(v0.z); BsT[ns+3][kk] = f2b(v0.w);
      BsT[ns+4][kk] = f2b(v1.x); BsT[ns+5][kk] = f2b(v1.y);
      BsT[ns+6][kk] = f2b(v1.z); BsT[ns+7][kk] = f2b(v1.w);
    }
    __syncthreads();
    const s16x8 af = *(const s16x8*)&As[(wave << 4) + l16][quad << 3];
    #pragma unroll
    for (int nt = 0; nt < 4; nt++) {
      const s16x8 bfr = *(const s16x8*)&BsT[(nt << 4) + l16][quad << 3];
      acc[nt] = mfma16(af, bfr, acc[nt]);
    }
  }
  const int mrow = m0 + (wave << 4) + (quad << 2);
  #pragma unroll
  for (int nt = 0; nt < 4; nt++) {
    const int n = n0 + (nt << 4) + l16;
    float badd = 0.f;
    if (MODE == 2) badd = bias[n];
    #pragma unroll
    for (int r = 0; r < 4; r++) {
      float v = acc[nt][r] + badd;
      if (MODE == 0)      ((u16*)Cout)[(size_t)(mrow + r) * N + n] = f2b(v);
      else if (MODE == 1) ((float*)Cout)[(size_t)n * M + (mrow + r)] = v;
      else                ((float*)Cout)[(size_t)(mrow + r) * N + n] = v;
    }
  }
}

// out[j] = sum_k A[j][k]*v[k] + c[j]   (tiny fp32 bias folds)
__global__ __launch_bounds__(256)
void bias_dot(const float* __restrict__ A, const float* __restrict__ v,
              const float* __restrict__ c, float* __restrict__ out,
              int M, int K) {
  int j = blockIdx.x * 256 + threadIdx.x;
  if (j >= M) return;
  const float* ar = A + (size_t)j * K;
  float acc = 0.f;
  for (int k = 0; k < K; k += 4) {
    float4 w = *(const float4*)(ar + k);
    acc += w.x * v[k] + w.y * v[k+1] + w.z * v[k+2] + w.w * v[k+3];
  }
  out[j] = acc + c[j];
}

// ---------------------------------------------------------------------------
// Phase 0: convert chunk_features fp32 [50000][768] -> bf16 [50048][768], pad=0
// ---------------------------------------------------------------------------
__global__ __launch_bounds__(256)
void convert_bf16(const float* __restrict__ src, u16* __restrict__ dst) {
  const size_t i = ((size_t)blockIdx.x * 256 + threadIdx.x) << 3;
  ushort4 lo, hi;
  if (i < (size_t)50000 * 768) {
    const float4 a = *(const float4*)(src + i);
    const float4 b = *(const float4*)(src + i + 4);
    lo.x = f2b(a.x); lo.y = f2b(a.y); lo.z = f2b(a.z); lo.w = f2b(a.w);
    hi.x = f2b(b.x); hi.y = f2b(b.y); hi.z = f2b(b.z); hi.w = f2b(b.w);
  } else {
    lo.x = lo.y = lo.z = lo.w = 0; hi.x = hi.y = hi.z = hi.w = 0;
  }
  *(ushort4*)(dst + i) = lo;
  *(ushort4*)(dst + i + 4) = hi;
}

// ---------------------------------------------------------------------------
// Phase 1: dense QKV projection, m97-style 128x128 tile, global_load_lds(16B)
// QKV[m][j] = sum_k Xb[m][k] * W[j][k] + bias[j],  M=50048, N=1536, K=768
// ---------------------------------------------------------------------------
__global__ __launch_bounds__(256)
void qkv_gemm(const u16* __restrict__ Xb, const u16* __restrict__ W,
              const float* __restrict__ bias, u16* __restrict__ QKV) {
  __shared__ u16 As[128 * 32];
  __shared__ u16 Bs[128 * 32];
  const int tid = threadIdx.x;
  const int wave = tid >> 6, lane = tid & 63;
  const int wm = wave >> 1, wn = wave & 1;
  const int quad = lane >> 4, l16 = lane & 15;
  const int m0 = blockIdx.y << 7, n0 = blockIdx.x << 7;

  // staging: wave w covers tile rows [w*32, w*32+32), two 16-row instructions
  const int r0 = (wave << 5) + (lane >> 2);
  const int cb = (lane & 3) << 3;                      // u16 offset in k-slice
  const u16* gA = Xb + (size_t)(m0 + r0) * 768 + cb;
  const u16* gB = W  + (size_t)(n0 + r0) * 768 + cb;
  u16* lA = As + (wave << 10);
  u16* lB = Bs + (wave << 10);

  f32x4 acc[4][4];
  #pragma unroll
  for (int i = 0; i < 4; i++)
    #pragma unroll
    for (int j = 0; j < 4; j++) acc[i][j] = (f32x4){0.f, 0.f, 0.f, 0.f};

  for (int k0 = 0; k0 < 768; k0 += 32) {
    __syncthreads();
    gld_lds16(gA + k0,            lA);
    gld_lds16(gA + k0 + 16 * 768, lA + 512);
    gld_lds16(gB + k0,            lB);
    gld_lds16(gB + k0 + 16 * 768, lB + 512);
    __syncthreads();
    s16x8 af[4], bf[4];
    #pragma unroll
    for (int i = 0; i < 4; i++)
      af[i] = *(const s16x8*)(As + ((wm << 6) + (i << 4) + l16) * 32 + (quad << 3));
    #pragma unroll
    for (int j = 0; j < 4; j++)
      bf[j] = *(const s16x8*)(Bs + ((wn << 6) + (j << 4) + l16) * 32 + (quad << 3));
    #pragma unroll
    for (int i = 0; i < 4; i++)
      #pragma unroll
      for (int j = 0; j < 4; j++)
        acc[i][j] = mfma16(af[i], bf[j], acc[i][j]);
  }

  #pragma unroll
  for (int j = 0; j < 4; j++) {
    const int col = n0 + (wn << 6) + (j << 4) + l16;
    const float badd = bias[col];
    #pragma unroll
    for (int i = 0; i < 4; i++) {
      const int row = m0 + (wm << 6) + (i << 4) + (quad << 2);
      #pragma unroll
      for (int r = 0; r < 4; r++)
        QKV[(size_t)(row + r) * 1536 + col] = f2b(acc[i][j][r] + badd);
    }
  }
}

// ---------------------------------------------------------------------------
// Phase 2: per-(cell,head) attention + masked mean-pool.
// QKV row layout: [0,512) Q (h*64+d), [512,1024) K, [1024,1536) V, bf16.
// Q/K MFMA fragments are gathered straight from global (16B per lane).
// ---------------------------------------------------------------------------
__global__ __launch_bounds__(256)
void attn2(const u16* __restrict__ QKV, const int* __restrict__ cell_idx,
           const int* __restrict__ cell_len, float* __restrict__ pooled_g) {
  __shared__ int idx_s[64];
  __shared__ u16 VT[64][72];     // V transposed: [d][m]
  __shared__ u16 Ps[64][72];     // softmax probs (bf16), A-layout
  __shared__ float Sf[64][66];   // scores / ctx staging
  __shared__ float pp[4][64];

  const int c = blockIdx.x, h = blockIdx.y;
  const int tid = threadIdx.x;
  const int wave = tid >> 6, lane = tid & 63;
  const int quad = lane >> 4, l16 = lane & 15;

  int len = cell_len[c];
  len = (len < 1) ? 1 : ((len > 64) ? 64 : len);
  const int mt = (len + 15) >> 4;
  const int Lr = mt << 4;
  const int kpv = (len + 31) >> 5;
  const float invLen = 1.0f / (float)len;

  if (tid < 64) idx_s[tid] = cell_idx[(c << 6) + tid];
  { // zero VT and Ps (garbage cols must contribute exactly 0, never NaN)
    const ushort4 z = {0, 0, 0, 0};
    u16* vz = &VT[0][0];
    u16* pz = &Ps[0][0];
    for (int i = tid; i < 1152; i += 256) {
      *(ushort4*)(vz + (i << 2)) = z;
      *(ushort4*)(pz + (i << 2)) = z;
    }
  }
  __syncthreads();

  // gather V transposed into LDS
  for (int i = tid; i < (len << 3); i += 256) {
    const int r = i >> 3, seg = i & 7;
    const u16* src = QKV + (size_t)idx_s[r] * 1536 + 1024 + (h << 6) + (seg << 3);
    const ushort4 a = *(const ushort4*)src;
    const ushort4 b = *(const ushort4*)(src + 4);
    const int d0 = seg << 3;
    VT[d0+0][r] = a.x; VT[d0+1][r] = a.y; VT[d0+2][r] = a.z; VT[d0+3][r] = a.w;
    VT[d0+4][r] = b.x; VT[d0+5][r] = b.y; VT[d0+6][r] = b.z; VT[d0+7][r] = b.w;
  }

  // S = Q K^T  (fragments straight from global; rows >= len are garbage-but-
  // finite and get masked in softmax / excluded from pool)
  for (int item = wave; item < mt * mt; item += 4) {
    const int mq = item / mt, mk = item - mq * mt;
    const size_t qrow = (size_t)idx_s[(mq << 4) + l16] * 1536;
    const size_t krow = (size_t)idx_s[(mk << 4) + l16] * 1536;
    f32x4 s = {0.f, 0.f, 0.f, 0.f};
    #pragma unroll
    for (int ks = 0; ks < 2; ks++) {
      const s16x8 a = *(const s16x8*)(QKV + qrow + (h << 6) + (ks << 5) + (quad << 3));
      const s16x8 b = *(const s16x8*)(QKV + krow + 512 + (h << 6) + (ks << 5) + (quad << 3));
      s = mfma16(a, b, s);
    }
    const int col = (mk << 4) + l16, rb = (mq << 4) + (quad << 2);
    Sf[rb+0][col] = s[0]; Sf[rb+1][col] = s[1];
    Sf[rb+2][col] = s[2]; Sf[rb+3][col] = s[3];
  }
  __syncthreads();

  // softmax: 4 threads per row, shuffle-combine
  {
    const int row = tid >> 2, sub = tid & 3, c0 = sub << 4;
    if (row < Lr) {
      float ev[16];
      float mx = -3e38f;
      #pragma unroll
      for (int t = 0; t < 16; t++) {
        const int cc = c0 + t;
        const float v = (cc < len) ? Sf[row][cc] : -3e38f;
        ev[t] = v; mx = fmaxf(mx, v);
      }
      mx = fmaxf(mx, __shfl_xor(mx, 1));
      mx = fmaxf(mx, __shfl_xor(mx, 2));
      float sum = 0.f;
      #pragma unroll
      for (int t = 0; t < 16; t++) {
        const int cc = c0 + t;
        const float e = (cc < len) ? __expf((ev[t] - mx) * 0.125f) : 0.f;
        ev[t] = e; sum += e;
      }
      sum += __shfl_xor(sum, 1);
      sum += __shfl_xor(sum, 2);
      const float inv = 1.0f / sum;
      #pragma unroll
      for (int t = 0; t < 16; t++) {
        const int cc = c0 + t;
        if (cc < len) Ps[row][cc] = f2b(ev[t] * inv);
      }
    }
  }
  __syncthreads();

  // ctx = P @ V (via VT)
  for (int item = wave; item < (mt << 2); item += 4) {
    const int mq = item >> 2, nd = item & 3;
    f32x4 s = {0.f, 0.f, 0.f, 0.f};
    for (int ks = 0; ks < kpv; ks++) {
      const s16x8 a = *(const s16x8*)&Ps[(mq << 4) + l16][(ks << 5) + (quad << 3)];
      const s16x8 b = *(const s16x8*)&VT[(nd << 4) + l16][(ks << 5) + (quad << 3)];
      s = mfma16(a, b, s);
    }
    const int col = (nd << 4) + l16, rb = (mq << 4) + (quad << 2);
    Sf[rb+0][col] = s[0]; Sf[rb+1][col] = s[1];
    Sf[rb+2][col] = s[2]; Sf[rb+3][col] = s[3];
  }
  __syncthreads();

  // masked mean-pool
  {
    float s = 0.f;
    for (int l = wave; l < len; l += 4) s += Sf[l][lane];
    pp[wave][lane] = s;
  }
  __syncthreads();
  if (tid < 64) {
    const float s = (pp[0][tid] + pp[1][tid] + pp[2][tid] + pp[3][tid]) * invLen;
    pooled_g[((size_t)c << 9) + (h << 6) + tid] = s;
  }
}

// ---------------------------------------------------------------------------
// Fallback (round-0 proven path): fused per-cell attention, 1 block/cell.
// ---------------------------------------------------------------------------
template<int MT>
static __device__ __forceinline__ void heads_loop(
    const u16* __restrict__ Wqkv, const float* __restrict__ b_eff,
    u16 (*Xs)[776], u16 (*Qs)[72], u16 (*Ks)[72], u16 (*VTs)[72],
    u16 (*Psf)[72], float (*Sf)[65], float* pooled,
    const int len, const float invLen, const int tid) {
  const int wave = tid >> 6, lane = tid & 63;
  const int quad = lane >> 4, l16 = lane & 15;
  constexpr int LR = MT * 16;
  constexpr int KPV = (LR + 31) / 32;
  const float scale = 0.125f;

  for (int h = 0; h < 8; h++) {
    f32x4 acc[3][MT];
    #pragma unroll
    for (int it = 0; it < 3; it++)
      #pragma unroll
      for (int im = 0; im < MT; im++) acc[it][im] = (f32x4){0.f,0.f,0.f,0.f};
    int grow[3], jcol[3];
    #pragma unroll
    for (int it = 0; it < 3; it++) {
      const int j = ((wave * 3 + it) << 4) + l16;
      const int sec = j >> 6;
      grow[it] = (sec << 9) + (h << 6) + (j & 63);
      jcol[it] = j;
    }
    s16x8 bcur[3];
    #pragma unroll
    for (int it = 0; it < 3; it++)
      bcur[it] = *(const s16x8*)(Wqkv + (size_t)grow[it] * 768 + (quad << 3));
    for (int ks = 0; ks < 24; ks++) {
      s16x8 bnext[3];
      const int ksn = (ks < 23) ? (ks + 1) : 23;
      #pragma unroll
      for (int it = 0; it < 3; it++)
        bnext[it] = *(const s16x8*)(Wqkv + (size_t)grow[it] * 768 + (ksn << 5) + (quad << 3));
      s16x8 af[MT];
      #pragma unroll
      for (int im = 0; im < MT; im++)
        af[im] = *(const s16x8*)&Xs[(im << 4) + l16][(ks << 5) + (quad << 3)];
      #pragma unroll
      for (int it = 0; it < 3; it++)
        #pragma unroll
        for (int im = 0; im < MT; im++)
          acc[it][im] = mfma16(af[im], bcur[it], acc[it][im]);
      bcur[0] = bnext[0]; bcur[1] = bnext[1]; bcur[2] = bnext[2];
    }
    #pragma unroll
    for (int it = 0; it < 3; it++) {
      const float badd = b_eff[grow[it]];
      const int j = jcol[it];
      #pragma unroll
      for (int im = 0; im < MT; im++) {
        const int rb = (im << 4) + (quad << 2);
        if (j < 64) {
          #pragma unroll
          for (int r = 0; r < 4; r++) Qs[rb + r][j] = f2b(acc[it][im][r] + badd);
        } else if (j < 128) {
          #pragma unroll
          for (int r = 0; r < 4; r++) Ks[rb + r][j - 64] = f2b(acc[it][im][r] + badd);
        } else {
          ushort4 hv;
          hv.x = f2b(acc[it][im][0] + badd);
          hv.y = f2b(acc[it][im][1] + badd);
          hv.z = f2b(acc[it][im][2] + badd);
          hv.w = f2b(acc[it][im][3] + badd);
          *(ushort4*)&VTs[j - 128][rb] = hv;
        }
      }
    }
    __syncthreads();
    for (int item = wave; item < MT * MT; item += 4) {
      const int mq = item / MT, mk = item - mq * MT;
      f32x4 sacc = (f32x4){0.f,0.f,0.f,0.f};
      #pragma unroll
      for (int ks = 0; ks < 2; ks++) {
        const s16x8 a = *(const s16x8*)&Qs[(mq << 4) + l16][(ks << 5) + (quad << 3)];
        const s16x8 b = *(const s16x8*)&Ks[(mk << 4) + l16][(ks << 5) + (quad << 3)];
        sacc = mfma16(a, b, sacc);
      }
      const int col = (mk << 4) + l16;
      const int rb = (mq << 4) + (quad << 2);
      #pragma unroll
      for (int r = 0; r < 4; r++) Sf[rb + r][col] = sacc[r];
    }
    __syncthreads();
    if (tid < LR) {
      float mx = -1e30f;
      for (int m = 0; m < len; m++) mx = fmaxf(mx, Sf[tid][m]);
      float sum = 0.f;
      for (int m = 0; m < len; m++) {
        const float e = __expf((Sf[tid][m] - mx) * scale);
        Sf[tid][m] = e;
        sum += e;
      }
      const float inv = 1.0f / sum;
      for (int m = 0; m < len; m++) Psf[tid][m] = f2b(Sf[tid][m] * inv);
    }
    __syncthreads();
    for (int item = wave; item < MT * 4; item += 4) {
      const int mq = item >> 2, nd = item & 3;
      f32x4 cacc = (f32x4){0.f,0.f,0.f,0.f};
      #pragma unroll
      for (int ks = 0; ks < KPV; ks++) {
        const s16x8 a = *(const s16x8*)&Psf[(mq << 4) + l16][(ks << 5) + (quad << 3)];
        const s16x8 b = *(const s16x8*)&VTs[(nd << 4) + l16][(ks << 5) + (quad << 3)];
        cacc = mfma16(a, b, cacc);
      }
      const int col = (nd << 4) + l16;
      const int rb = (mq << 4) + (quad << 2);
      #pragma unroll
      for (int r = 0; r < 4; r++) Sf[rb + r][col] = cacc[r];
    }
    __syncthreads();
    if (tid < 64) {
      float s = 0.f;
      for (int l = 0; l < len; l++) s += Sf[l][tid];
      pooled[(h << 6) + tid] = s * invLen;
    }
    __syncthreads();
  }
}

__global__ __launch_bounds__(256, 1)
void cell_attn(const float* __restrict__ chunk, const u16* __restrict__ Wqkv,
               const float* __restrict__ b_eff, const int* __restrict__ cell_idx,
               const int* __restrict__ cell_len, float* __restrict__ pooled_g) {
  __shared__ u16 Xs[64][776];
  __shared__ u16 Qs[64][72];
  __shared__ u16 Ks[64][72];
  __shared__ u16 VTs[64][72];
  __shared__ u16 Psf[64][72];
  __shared__ float Sf[64][65];
  __shared__ float pooled[512];
  __shared__ int idx_s[64];

  const int c = blockIdx.x;
  const int tid = threadIdx.x;

  int len = cell_len[c];
  len = (len < 1) ? 1 : ((len > 64) ? 64 : len);
  const int mt = (len + 15) >> 4;
  const int Lr = mt << 4;
  const float invLen = 1.0f / (float)len;

  if (tid < 64) idx_s[tid] = cell_idx[(c << 6) + tid];
  __syncthreads();

  for (int i = tid; i < len * 192; i += 256) {
    const int r = i / 192;
    const int c4 = i - r * 192;
    const float4 f = *(const float4*)(chunk + (size_t)idx_s[r] * 768 + (c4 << 2));
    ushort4 hv; hv.x = f2b(f.x); hv.y = f2b(f.y); hv.z = f2b(f.z); hv.w = f2b(f.w);
    *(ushort4*)&Xs[r][c4 << 2] = hv;
  }
  const ushort4 z4 = {0, 0, 0, 0};
  for (int i = tid; i < (Lr - len) * 192; i += 256) {
    const int r = len + i / 192;
    const int c4 = i - (i / 192) * 192;
    *(ushort4*)&Xs[r][c4 << 2] = z4;
  }
  for (int i = tid; i < 1152; i += 256) *(ushort4*)(&Psf[0][0] + (i << 2)) = z4;
  for (int i = tid; i < 1152; i += 256) *(ushort4*)(&VTs[0][0] + (i << 2)) = z4;
  __syncthreads();

  switch (mt) {
    case 1: heads_loop<1>(Wqkv, b_eff, Xs, Qs, Ks, VTs, Psf, Sf, pooled, len, invLen, tid); break;
    case 2: heads_loop<2>(Wqkv, b_eff, Xs, Qs, Ks, VTs, Psf, Sf, pooled, len, invLen, tid); break;
    case 3: heads_loop<3>(Wqkv, b_eff, Xs, Qs, Ks, VTs, Psf, Sf, pooled, len, invLen, tid); break;
    default: heads_loop<4>(Wqkv, b_eff, Xs, Qs, Ks, VTs, Psf, Sf, pooled, len, invLen, tid); break;
  }

  for (int i = tid; i < 512; i += 256) pooled_g[((size_t)c << 9) + i] = pooled[i];
}

// ---------------------------------------------------------------------------
extern "C" void kernel_launch(void* const* d_in, const int* in_sizes, int n_in,
                              void* d_out, int out_size, void* d_ws, size_t ws_size,
                              hipStream_t stream) {
  const float* chunk  = (const float*)d_in[0];
  const float* Wq     = (const float*)d_in[1];
  const float* bq     = (const float*)d_in[2];
  const float* Wk     = (const float*)d_in[3];
  const float* bk     = (const float*)d_in[4];
  const float* Wv     = (const float*)d_in[5];
  const float* bv     = (const float*)d_in[6];
  const float* W_in   = (const float*)d_in[7];
  const float* b_in   = (const float*)d_in[8];
  const float* Wo     = (const float*)d_in[9];
  const float* bo     = (const float*)d_in[10];
  const float* Wout   = (const float*)d_in[11];
  const float* bout   = (const float*)d_in[12];
  const int* cell_idx = (const int*)d_in[13];
  const int* cell_len = (const int*)d_in[14];

  // workspace layout
  char* ws = (char*)d_ws;
  u16*   Wqkv   = (u16*)(ws + 0);              // [1536][768] bf16 fused qkv weights
  float* b_eff  = (float*)(ws + 2359296);      // [1536]
  float* WfT    = (float*)(ws + 2365440);      // [512][256] (Wout@Wo)^T fp32
  float* bfe    = (float*)(ws + 2889728);      // [256]
  float* pooled = (float*)(ws + 2890752);      // [2048][512] fp32
  u16*   Xb     = (u16*)(ws + 7085056);        // [50048][768] bf16
  u16*   QKV    = (u16*)(ws + 83958784);       // [50048][1536] bf16
  const size_t FAST_NEED = 237706240ull;       // end of QKV
  const bool fast = (ws_size >= FAST_NEED);

  dim3 blk(256);
  // fused projection weights: W{q,k,v}_eff = W_in[block] @ W{q,k,v}
  dim3 g1(12, 8);
  gemm_pre<0><<<g1, blk, 0, stream>>>(W_in,            Wq, (void*)(Wqkv),            nullptr, 512, 768, 512);
  gemm_pre<0><<<g1, blk, 0, stream>>>(W_in + 512*512,  Wk, (void*)(Wqkv + 512*768),  nullptr, 512, 768, 512);
  gemm_pre<0><<<g1, blk, 0, stream>>>(W_in + 1024*512, Wv, (void*)(Wqkv + 1024*768), nullptr, 512, 768, 512);
  dim3 g2(8, 4);
  gemm_pre<1><<<g2, blk, 0, stream>>>(Wout, Wo, (void*)WfT, nullptr, 256, 512, 512);
  bias_dot<<<dim3(2), blk, 0, stream>>>(W_in,            bq, b_in,        b_eff,        512, 512);
  bias_dot<<<dim3(2), blk, 0, stream>>>(W_in + 512*512,  bk, b_in + 512,  b_eff + 512,  512, 512);
  bias_dot<<<dim3(2), blk, 0, stream>>>(W_in + 1024*512, bv, b_in + 1024, b_eff + 1024, 512, 512);
  bias_dot<<<dim3(1), blk, 0, stream>>>(Wout, bo, bout, bfe, 256, 512);

  if (fast) {
    convert_bf16<<<dim3(18768), blk, 0, stream>>>(chunk, Xb);
    qkv_gemm<<<dim3(12, 391), blk, 0, stream>>>(Xb, Wqkv, b_eff, QKV);
    attn2<<<dim3(2048, 8), blk, 0, stream>>>(QKV, cell_idx, cell_len, pooled);
  } else {
    cell_attn<<<dim3(2048), blk, 0, stream>>>(chunk, Wqkv, b_eff, cell_idx, cell_len, pooled);
  }

  dim3 g3(4, 32);
  gemm_pre<2><<<g3, blk, 0, stream>>>(pooled, WfT, d_out, bfe, 2048, 256, 512);
}